// Round 9
// baseline (61.966 us; speedup 1.0000x reference)
//
#include <hip/hip_runtime.h>
#include <hip/hip_bf16.h>

// Problem constants (B=8, S=512, D=256, M=64, DE=256, H=8, DH=32).
// entity_mask == 0 always (softmax rows sum to 1 -> activity = 1/512 < 0.1),
// so graph output is exactly zero; only `entities` needs compute.
//
// Round 9: attention moved to MFMA (was vector-fp32 with a 13.7us VALU
// floor). Per (b,h) block: QK^T split-bf16 MFMA -> full-row softmax ->
// P staged bf16 hi/lo in LDS -> PV as ctx^T = V^T * P^T (swapped, so all
// frags contiguous) -> cross-wave reduce in LDS. 4 dispatches:
// preproc, gemm_kv(direct, bf16 K/V^T epilogue), attn_mfma, gemm_wo(direct).

typedef unsigned short ushort_t;
typedef __attribute__((ext_vector_type(8))) short short8;
typedef __attribute__((ext_vector_type(4))) short short4v;
typedef __attribute__((ext_vector_type(4))) float f32x4;

__device__ __forceinline__ ushort_t f2bf(float f) {
    unsigned u = __builtin_bit_cast(unsigned, f);
    unsigned r = (u + 0x7fff + ((u >> 16) & 1)) >> 16;   // RNE
    return (ushort_t)r;
}
__device__ __forceinline__ float bf2f(ushort_t h) {
    return __builtin_bit_cast(float, (unsigned)h << 16);
}

// ---------------- P: fused preprocessing ----------------
// [0,1024):    x = emb+pos -> xh/xl
// [1024,1536): wk|wv -> bt_h/bt_l TRANSPOSED [512 n][256 k] hi/lo
// [1536,1792): wo -> wt_h/wt_l TRANSPOSED [256 n][256 k] hi/lo
// [1792,1856): qproj -> qh/ql bf16 [h][64 m][32 dh] (scale folded in)
// [1856,1889): zero graph+mask tail of d_out
__global__ __launch_bounds__(256) void preproc_kernel(
        const float* __restrict__ emb, const float* __restrict__ pos,
        const float* __restrict__ wk, const float* __restrict__ wv,
        const float* __restrict__ wo, const float* __restrict__ lib,
        const float* __restrict__ wq,
        ushort_t* __restrict__ xh, ushort_t* __restrict__ xl,
        ushort_t* __restrict__ bt_h, ushort_t* __restrict__ bt_l,
        ushort_t* __restrict__ wt_h, ushort_t* __restrict__ wt_l,
        ushort_t* __restrict__ qh, ushort_t* __restrict__ ql,
        float4* __restrict__ tail) {
    __shared__ float sh[256];
    __shared__ ushort_t th[16][17], tl[16][17];
    const int blk = blockIdx.x, tid = threadIdx.x;
    if (blk < 1024) {
        int i = blk * 256 + tid;
        int dq = i & 63, s = (i >> 6) & 511;
        float4 e = ((const float4*)emb)[i];
        float4 p = ((const float4*)pos)[(s << 6) + dq];
        float v[4] = {e.x + p.x, e.y + p.y, e.z + p.z, e.w + p.w};
        ushort_t h0 = f2bf(v[0]), h1 = f2bf(v[1]), h2 = f2bf(v[2]), h3 = f2bf(v[3]);
        ushort_t l0 = f2bf(v[0] - bf2f(h0)), l1 = f2bf(v[1] - bf2f(h1));
        ushort_t l2 = f2bf(v[2] - bf2f(h2)), l3 = f2bf(v[3] - bf2f(h3));
        ((uint2*)xh)[i] = make_uint2((unsigned)h0 | ((unsigned)h1 << 16),
                                     (unsigned)h2 | ((unsigned)h3 << 16));
        ((uint2*)xl)[i] = make_uint2((unsigned)l0 | ((unsigned)l1 << 16),
                                     (unsigned)l2 | ((unsigned)l3 << 16));
    } else if (blk < 1536) {
        int tt = blk - 1024;                          // 0..511
        int kt = tt & 15, ntile = tt >> 4;
        int r = tid >> 4, c = tid & 15;
        int n = ntile * 16 + c, k = kt * 16 + r;
        float v = (n < 256) ? wk[(size_t)k * 256 + n] : wv[(size_t)k * 256 + n - 256];
        ushort_t h = f2bf(v);
        th[r][c] = h;
        tl[r][c] = f2bf(v - bf2f(h));
        __syncthreads();
        int c2 = tid >> 4, r2 = tid & 15;
        size_t o = (size_t)(ntile * 16 + c2) * 256 + kt * 16 + r2;
        bt_h[o] = th[r2][c2];
        bt_l[o] = tl[r2][c2];
    } else if (blk < 1792) {
        int tt = blk - 1536;                          // 0..255
        int kt = tt >> 4, nt = tt & 15;
        int r = tid >> 4, c = tid & 15;
        float v = wo[(size_t)(kt * 16 + r) * 256 + nt * 16 + c];
        ushort_t h = f2bf(v);
        th[r][c] = h;
        tl[r][c] = f2bf(v - bf2f(h));
        __syncthreads();
        int c2 = tid >> 4, r2 = tid & 15;
        size_t o = (size_t)(nt * 16 + c2) * 256 + kt * 16 + r2;
        wt_h[o] = th[r2][c2];
        wt_l[o] = tl[r2][c2];
    } else if (blk < 1856) {
        int m = blk - 1792;
        sh[tid] = lib[m * 256 + tid];
        __syncthreads();
        float acc = 0.f;
        #pragma unroll 8
        for (int d = 0; d < 256; ++d) acc = fmaf(sh[d], wq[d * 256 + tid], acc);
        acc *= 0.17677669529663687f;                  // 1/sqrt(32)
        int hh = tid >> 5, dd = tid & 31;
        ushort_t hv = f2bf(acc);
        size_t o = (size_t)(hh * 64 + m) * 32 + dd;
        qh[o] = hv;
        ql[o] = f2bf(acc - bf2f(hv));
    } else {
        int i = (blk - 1856) * 256 + tid;
        if (i < 8320) tail[i] = make_float4(0.f, 0.f, 0.f, 0.f);
    }
}

// ---------------- K|V projection: direct-load split-bf16 MFMA GEMM ----------------
// C[4096,512] = (xh+xl) @ (bt_h+bt_l)^T-given; epilogue writes bf16 hi/lo:
//   cols [0,256)  -> K  at kh/kl [(b*8+h)*512 + s][32]
//   cols [256,512)-> V^T at vth/vtl [(b*8+h)*32 + dh][512]
__global__ __launch_bounds__(256) void gemm_kv_direct_kernel(
        const ushort_t* __restrict__ Ah, const ushort_t* __restrict__ Al,
        const ushort_t* __restrict__ Bth, const ushort_t* __restrict__ Btl,
        ushort_t* __restrict__ kh, ushort_t* __restrict__ kl,
        ushort_t* __restrict__ vth, ushort_t* __restrict__ vtl) {
    const int tid = threadIdx.x;
    const int w = tid >> 6, l = tid & 63;
    const int wr = w >> 1, wc = w & 1;
    const int m0 = blockIdx.x * 128;
    const int n0 = blockIdx.y * 64;
    const int l15 = l & 15, lk8 = (l >> 4) * 8;

    short8 bhf[2][8];
    #pragma unroll
    for (int j = 0; j < 2; ++j) {
        const size_t base = (size_t)(n0 + wc * 32 + j * 16 + l15) * 256 + lk8;
        #pragma unroll
        for (int kf = 0; kf < 8; ++kf)
            bhf[j][kf] = *(const short8*)(Bth + base + kf * 32);
    }

    f32x4 acc[4][2];
    #pragma unroll
    for (int i = 0; i < 4; ++i)
        #pragma unroll
        for (int j = 0; j < 2; ++j) acc[i][j] = (f32x4){0.f, 0.f, 0.f, 0.f};

    #pragma unroll
    for (int kf = 0; kf < 8; ++kf) {
        short8 blf[2];
        #pragma unroll
        for (int j = 0; j < 2; ++j)
            blf[j] = *(const short8*)(Btl + (size_t)(n0 + wc * 32 + j * 16 + l15) * 256 + kf * 32 + lk8);
        #pragma unroll
        for (int i = 0; i < 4; ++i) {
            const size_t ab = (size_t)(m0 + wr * 64 + i * 16 + l15) * 256 + kf * 32 + lk8;
            short8 a_h = *(const short8*)(Ah + ab);
            short8 a_l = *(const short8*)(Al + ab);
            #pragma unroll
            for (int j = 0; j < 2; ++j) {
                acc[i][j] = __builtin_amdgcn_mfma_f32_16x16x32_bf16(a_h, bhf[j][kf], acc[i][j], 0, 0, 0);
                acc[i][j] = __builtin_amdgcn_mfma_f32_16x16x32_bf16(a_l, bhf[j][kf], acc[i][j], 0, 0, 0);
                acc[i][j] = __builtin_amdgcn_mfma_f32_16x16x32_bf16(a_h, blf[j], acc[i][j], 0, 0, 0);
            }
        }
    }

    // epilogue: C row = (l>>4)*4+reg (s global), col = l15 (h*32+dh)
    #pragma unroll
    for (int i = 0; i < 4; ++i) {
        #pragma unroll
        for (int j = 0; j < 2; ++j) {
            const int col = n0 + wc * 32 + j * 16 + l15;
            const int rowb = m0 + wr * 64 + i * 16 + (l >> 4) * 4;
            const int bb = rowb >> 9, ss = rowb & 511;
            if (col < 256) {                      // K (branch uniform per block)
                const int hh = col >> 5, dd = col & 31;
                const size_t o = ((size_t)((bb * 8 + hh) * 512 + ss)) * 32 + dd;
                #pragma unroll
                for (int r = 0; r < 4; ++r) {
                    float val = acc[i][j][r];
                    ushort_t hv = f2bf(val);
                    kh[o + (size_t)r * 32] = hv;
                    kl[o + (size_t)r * 32] = f2bf(val - bf2f(hv));
                }
            } else {                              // V^T
                const int c2 = col - 256, hh = c2 >> 5, dd = c2 & 31;
                const size_t o = ((size_t)((bb * 8 + hh) * 32 + dd)) * 512 + ss;
                short4v hv4, lv4;
                #pragma unroll
                for (int r = 0; r < 4; ++r) {
                    float val = acc[i][j][r];
                    ushort_t hv = f2bf(val);
                    hv4[r] = (short)hv;
                    lv4[r] = (short)f2bf(val - bf2f(hv));
                }
                *(short4v*)(vth + o) = hv4;
                *(short4v*)(vtl + o) = lv4;
            }
        }
    }
}

// ---------------- MFMA attention: one block per (b,h) ----------------
// 256 thr = 4 waves; wave w owns s in [w*128,(w+1)*128).
// QK^T: A=Q[m][dh] frags, B=K[s][dh] frags (3-term split) -> S in C-layout.
// Softmax: 16-lane shuffle row-reduce + cross-wave LDS (full row, no online).
// PV (swapped): ctx^T = V^T * P^T; A=V^T[dh][s] global frags, B=P^T from
// per-wave LDS (P written bf16 hi/lo in s-quarters). Cross-wave PV reduce
// through LDS (aliased over P region, barrier-separated).
__global__ __launch_bounds__(256) void attn_mfma_kernel(
        const ushort_t* __restrict__ qh, const ushort_t* __restrict__ ql,
        const ushort_t* __restrict__ kh, const ushort_t* __restrict__ kl,
        const ushort_t* __restrict__ vth, const ushort_t* __restrict__ vtl,
        ushort_t* __restrict__ ch, ushort_t* __restrict__ cl) {
    __shared__ float sMax[4][64], sSum[4][64];
    __shared__ __align__(16) unsigned char sbig[40960];
    ushort_t* PhB = (ushort_t*)sbig;             // [4][64][40]
    ushort_t* PlB = (ushort_t*)(sbig + 20480);   // [4][64][40]
    float* red = (float*)sbig;                   // [4][64][36] (aliased later)

    const int bh = blockIdx.x;
    const int b = bh >> 3, h = bh & 7;
    const int tid = threadIdx.x;
    const int w = tid >> 6, l = tid & 63;
    const int l15 = l & 15, lg = l >> 4, lk8 = lg * 8;

    // Q fragments (A-operand): m = i*16+l15, k(dh) = lk8..+8
    short8 aqh[4], aql[4];
    #pragma unroll
    for (int i = 0; i < 4; ++i) {
        const size_t o = (size_t)(h * 64 + i * 16 + l15) * 32 + lk8;
        aqh[i] = *(const short8*)(qh + o);
        aql[i] = *(const short8*)(ql + o);
    }

    // ---- QK^T ----
    f32x4 sa[4][8];
    #pragma unroll
    for (int i = 0; i < 4; ++i)
        #pragma unroll
        for (int nt = 0; nt < 8; ++nt) sa[i][nt] = (f32x4){0.f, 0.f, 0.f, 0.f};
    const size_t kb = (size_t)bh * 512 * 32;
    #pragma unroll
    for (int nt = 0; nt < 8; ++nt) {
        const size_t o = kb + (size_t)(w * 128 + nt * 16 + l15) * 32 + lk8;
        short8 bkh = *(const short8*)(kh + o);
        short8 bkl = *(const short8*)(kl + o);
        #pragma unroll
        for (int i = 0; i < 4; ++i) {
            sa[i][nt] = __builtin_amdgcn_mfma_f32_16x16x32_bf16(aqh[i], bkh, sa[i][nt], 0, 0, 0);
            sa[i][nt] = __builtin_amdgcn_mfma_f32_16x16x32_bf16(aql[i], bkh, sa[i][nt], 0, 0, 0);
            sa[i][nt] = __builtin_amdgcn_mfma_f32_16x16x32_bf16(aqh[i], bkl, sa[i][nt], 0, 0, 0);
        }
    }

    // ---- softmax: row = m = i*16 + lg*4 + p; cols spread over l15 and nt ----
    float rm[4][4];
    #pragma unroll
    for (int i = 0; i < 4; ++i)
        #pragma unroll
        for (int p = 0; p < 4; ++p) {
            float v = sa[i][0][p];
            #pragma unroll
            for (int nt = 1; nt < 8; ++nt) v = fmaxf(v, sa[i][nt][p]);
            rm[i][p] = v;
        }
    #pragma unroll
    for (int off = 1; off < 16; off <<= 1)
        #pragma unroll
        for (int i = 0; i < 4; ++i)
            #pragma unroll
            for (int p = 0; p < 4; ++p)
                rm[i][p] = fmaxf(rm[i][p], __shfl_xor(rm[i][p], off));
    if (l15 == 0) {
        #pragma unroll
        for (int i = 0; i < 4; ++i)
            #pragma unroll
            for (int p = 0; p < 4; ++p) sMax[w][i * 16 + lg * 4 + p] = rm[i][p];
    }
    __syncthreads();
    float gm[4][4];
    #pragma unroll
    for (int i = 0; i < 4; ++i)
        #pragma unroll
        for (int p = 0; p < 4; ++p) {
            const int m = i * 16 + lg * 4 + p;
            gm[i][p] = fmaxf(fmaxf(sMax[0][m], sMax[1][m]), fmaxf(sMax[2][m], sMax[3][m]));
        }
    float rs[4][4];
    #pragma unroll
    for (int i = 0; i < 4; ++i)
        #pragma unroll
        for (int p = 0; p < 4; ++p) rs[i][p] = 0.f;
    #pragma unroll
    for (int i = 0; i < 4; ++i)
        #pragma unroll
        for (int nt = 0; nt < 8; ++nt)
            #pragma unroll
            for (int p = 0; p < 4; ++p) {
                float e = __expf(sa[i][nt][p] - gm[i][p]);
                sa[i][nt][p] = e;
                rs[i][p] += e;
            }
    #pragma unroll
    for (int off = 1; off < 16; off <<= 1)
        #pragma unroll
        for (int i = 0; i < 4; ++i)
            #pragma unroll
            for (int p = 0; p < 4; ++p)
                rs[i][p] += __shfl_xor(rs[i][p], off);
    if (l15 == 0) {
        #pragma unroll
        for (int i = 0; i < 4; ++i)
            #pragma unroll
            for (int p = 0; p < 4; ++p) sSum[w][i * 16 + lg * 4 + p] = rs[i][p];
    }
    __syncthreads();

    // ---- PV in 4 s-quarters of 32: P -> LDS bf16 hi/lo, then MFMA ----
    f32x4 pa[2][4];
    #pragma unroll
    for (int a = 0; a < 2; ++a)
        #pragma unroll
        for (int n = 0; n < 4; ++n) pa[a][n] = (f32x4){0.f, 0.f, 0.f, 0.f};
    const size_t vb = (size_t)bh * 32 * 512;
    #pragma unroll
    for (int q = 0; q < 4; ++q) {
        #pragma unroll
        for (int e = 0; e < 2; ++e) {
            const int nt = q * 2 + e;
            #pragma unroll
            for (int i = 0; i < 4; ++i)
                #pragma unroll
                for (int p = 0; p < 4; ++p) {
                    const int mrow = i * 16 + lg * 4 + p;
                    const float v = sa[i][nt][p];
                    const ushort_t hv = f2bf(v);
                    PhB[(size_t)(w * 64 + mrow) * 40 + e * 16 + l15] = hv;
                    PlB[(size_t)(w * 64 + mrow) * 40 + e * 16 + l15] = f2bf(v - bf2f(hv));
                }
        }
        short8 bph[4], bpl[4];
        #pragma unroll
        for (int n = 0; n < 4; ++n) {
            bph[n] = *(const short8*)&PhB[(size_t)(w * 64 + n * 16 + l15) * 40 + lk8];
            bpl[n] = *(const short8*)&PlB[(size_t)(w * 64 + n * 16 + l15) * 40 + lk8];
        }
        #pragma unroll
        for (int a = 0; a < 2; ++a) {
            const size_t o = vb + (size_t)(a * 16 + l15) * 512 + w * 128 + q * 32 + lk8;
            short8 avh = *(const short8*)(vth + o);
            short8 avl = *(const short8*)(vtl + o);
            #pragma unroll
            for (int n = 0; n < 4; ++n) {
                pa[a][n] = __builtin_amdgcn_mfma_f32_16x16x32_bf16(avh, bph[n], pa[a][n], 0, 0, 0);
                pa[a][n] = __builtin_amdgcn_mfma_f32_16x16x32_bf16(avl, bph[n], pa[a][n], 0, 0, 0);
                pa[a][n] = __builtin_amdgcn_mfma_f32_16x16x32_bf16(avh, bpl[n], pa[a][n], 0, 0, 0);
            }
        }
    }

    // ---- cross-wave PV reduce (red aliases P region) ----
    __syncthreads();
    #pragma unroll
    for (int a = 0; a < 2; ++a)
        #pragma unroll
        for (int n = 0; n < 4; ++n)
            *(f32x4*)&red[(size_t)(w * 64 + l) * 36 + (a * 4 + n) * 4] = pa[a][n];
    __syncthreads();
    #pragma unroll
    for (int dd = 0; dd < 2; ++dd) {
        const int pr = w * 2 + dd;
        const int a = pr >> 2, n = pr & 3;
        f32x4 t0 = *(f32x4*)&red[(size_t)(0 * 64 + l) * 36 + pr * 4];
        f32x4 t1 = *(f32x4*)&red[(size_t)(1 * 64 + l) * 36 + pr * 4];
        f32x4 t2 = *(f32x4*)&red[(size_t)(2 * 64 + l) * 36 + pr * 4];
        f32x4 t3 = *(f32x4*)&red[(size_t)(3 * 64 + l) * 36 + pr * 4];
        const int m = n * 16 + l15;
        const float inv = 1.f / (sSum[0][m] + sSum[1][m] + sSum[2][m] + sSum[3][m]);
        short4v hv4, lv4;
        #pragma unroll
        for (int p = 0; p < 4; ++p) {
            const float val = (t0[p] + t1[p] + t2[p] + t3[p]) * inv;
            const ushort_t hv = f2bf(val);
            hv4[p] = (short)hv;
            lv4[p] = (short)f2bf(val - bf2f(hv));
        }
        const size_t o = (size_t)(b * 64 + m) * 256 + h * 32 + a * 16 + lg * 4;
        *(short4v*)(ch + o) = hv4;
        *(short4v*)(cl + o) = lv4;
    }
}

// ---------------- barrier-free direct-load split-bf16 MFMA GEMM (ctx @ wo) ----------------
__global__ __launch_bounds__(256) void gemm_direct_kernel(
        const ushort_t* __restrict__ Ah, const ushort_t* __restrict__ Al,
        const ushort_t* __restrict__ Bth, const ushort_t* __restrict__ Btl,
        float* __restrict__ out) {
    const int tid = threadIdx.x;
    const int w = tid >> 6, l = tid & 63;
    const int wr = w >> 1, wc = w & 1;
    const int m0 = blockIdx.x * 128;
    const int n0 = blockIdx.y * 64;
    const int l15 = l & 15, lk8 = (l >> 4) * 8;

    short8 bhf[2][8];
    #pragma unroll
    for (int j = 0; j < 2; ++j) {
        const size_t base = (size_t)(n0 + wc * 32 + j * 16 + l15) * 256 + lk8;
        #pragma unroll
        for (int kf = 0; kf < 8; ++kf)
            bhf[j][kf] = *(const short8*)(Bth + base + kf * 32);
    }

    f32x4 acc[4][2];
    #pragma unroll
    for (int i = 0; i < 4; ++i)
        #pragma unroll
        for (int j = 0; j < 2; ++j) acc[i][j] = (f32x4){0.f, 0.f, 0.f, 0.f};

    #pragma unroll
    for (int kf = 0; kf < 8; ++kf) {
        short8 blf[2];
        #pragma unroll
        for (int j = 0; j < 2; ++j)
            blf[j] = *(const short8*)(Btl + (size_t)(n0 + wc * 32 + j * 16 + l15) * 256 + kf * 32 + lk8);
        #pragma unroll
        for (int i = 0; i < 4; ++i) {
            const size_t ab = (size_t)(m0 + wr * 64 + i * 16 + l15) * 256 + kf * 32 + lk8;
            short8 a_h = *(const short8*)(Ah + ab);
            short8 a_l = *(const short8*)(Al + ab);
            #pragma unroll
            for (int j = 0; j < 2; ++j) {
                acc[i][j] = __builtin_amdgcn_mfma_f32_16x16x32_bf16(a_h, bhf[j][kf], acc[i][j], 0, 0, 0);
                acc[i][j] = __builtin_amdgcn_mfma_f32_16x16x32_bf16(a_l, bhf[j][kf], acc[i][j], 0, 0, 0);
                acc[i][j] = __builtin_amdgcn_mfma_f32_16x16x32_bf16(a_h, blf[j], acc[i][j], 0, 0, 0);
            }
        }
    }

    #pragma unroll
    for (int i = 0; i < 4; ++i) {
        #pragma unroll
        for (int j = 0; j < 2; ++j) {
            int col = n0 + wc * 32 + j * 16 + l15;
            int rowb = m0 + wr * 64 + i * 16 + (l >> 4) * 4;
            #pragma unroll
            for (int r = 0; r < 4; ++r)
                out[(size_t)(rowb + r) * 256 + col] = acc[i][j][r];
        }
    }
}

extern "C" void kernel_launch(void* const* d_in, const int* in_sizes, int n_in,
                              void* d_out, int out_size, void* d_ws, size_t ws_size,
                              hipStream_t stream) {
    const float* emb = (const float*)d_in[0];
    const float* lib = (const float*)d_in[2];
    const float* pos = (const float*)d_in[3];
    const float* wq  = (const float*)d_in[4];
    const float* wk  = (const float*)d_in[5];
    const float* wv  = (const float*)d_in[6];
    const float* wo  = (const float*)d_in[7];
    float* out = (float*)d_out;

    ushort_t* p = (ushort_t*)d_ws;
    ushort_t* xh   = p;              p += 1048576;   // x hi [4096][256]
    ushort_t* xl   = p;              p += 1048576;
    ushort_t* bt_h = p;              p += 131072;    // [wk|wv]^T [512][256]
    ushort_t* bt_l = p;              p += 131072;
    ushort_t* wt_h = p;              p += 65536;     // wo^T [256][256]
    ushort_t* wt_l = p;              p += 65536;
    ushort_t* qh   = p;              p += 16384;     // q [8][64][32]
    ushort_t* ql   = p;              p += 16384;
    ushort_t* kh   = p;              p += 1048576;   // K [64][512][32]
    ushort_t* kl   = p;              p += 1048576;
    ushort_t* vth  = p;              p += 1048576;   // V^T [64][32][512]
    ushort_t* vtl  = p;              p += 1048576;
    ushort_t* ch   = p;              p += 131072;    // ctx [512][256]
    ushort_t* cl   = p;              p += 131072;    // total ~13.7 MB

    preproc_kernel<<<1889, 256, 0, stream>>>(emb, pos, wk, wv, wo, lib, wq,
            xh, xl, bt_h, bt_l, wt_h, wt_l, qh, ql, (float4*)(out + 131072));

    gemm_kv_direct_kernel<<<dim3(32, 8), 256, 0, stream>>>(xh, xl, bt_h, bt_l,
            kh, kl, vth, vtl);

    attn_mfma_kernel<<<64, 256, 0, stream>>>(qh, ql, kh, kl, vth, vtl, ch, cl);

    gemm_direct_kernel<<<dim3(4, 4), 256, 0, stream>>>(ch, cl, wt_h, wt_l, out);
}